// Round 3
// baseline (1904.054 us; speedup 1.0000x reference)
//
#include <hip/hip_runtime.h>
#include <hip/hip_bf16.h>

// N=100000 nodes, 64 in-feats, 32 hidden, E=3200000 edges per type.
// Two-pass bucketed scatter: pass1 radix-bins edges by dst>>7 into 782
// buckets/type (packed 4B entries, L2-resident write frontier); pass2 does
// LDS-accumulated scatter + full epilogue per bucket. No global float atomics,
// no node-granular scattered writes (round-2 bin_kernel: 388MB writeback for
// a 25.6MB array = 15x amplification, 595us).

#define RS 128                 // dsts per bucket
#define RBITS 7
#define NBK ((100000 + RS - 1) / RS)   // 782 buckets per edge type
#define SCAN_BLOCK 1024
#define TILE 8192              // edges per pass1 block

// --- node in-degree counts (int, fire-and-forget) ---
__global__ void count_kernel(const int* __restrict__ ei_n, const int* __restrict__ ei_s,
                             int* __restrict__ cnt, int N, int En, int Es) {
    int gid = blockIdx.x * blockDim.x + threadIdx.x;
    if (gid < En) {
        atomicAdd(&cnt[ei_n[En + gid]], 1);
    } else if (gid < En + Es) {
        int e = gid - En;
        atomicAdd(&cnt[N + ei_s[Es + e]], 1);
    }
}

__global__ void dinv_kernel(const int* __restrict__ cnt, float* __restrict__ dinv, int M) {
    int i = blockIdx.x * blockDim.x + threadIdx.x;
    if (i < M) dinv[i] = rsqrtf((float)cnt[i] + 1.0f);   // +1 self-loop
}

// --- per-bucket counts from node counts (writes bcnt and a copy for scan) ---
__global__ void bucket_sum_kernel(const int* __restrict__ cnt,
                                  int* __restrict__ bcnt, int* __restrict__ bscan,
                                  int N, int M2) {
    int b = blockIdx.x * blockDim.x + threadIdx.x;
    if (b >= M2) return;
    int type = (b >= NBK) ? 1 : 0;
    int lo = (b - type * NBK) * RS;
    int hi = min(lo + RS, N);
    const int* c = cnt + (size_t)type * N;
    int s = 0;
    for (int i = lo; i < hi; ++i) s += c[i];
    bcnt[b] = s;
    bscan[b] = s;
}

// --- hierarchical inclusive scan over bscan[0..M) ---
__global__ void scan1_kernel(int* __restrict__ arr, int* __restrict__ bsum, int M) {
    __shared__ int s[SCAN_BLOCK];
    int i = blockIdx.x * SCAN_BLOCK + threadIdx.x;
    s[threadIdx.x] = (i < M) ? arr[i] : 0;
    __syncthreads();
#pragma unroll
    for (int off = 1; off < SCAN_BLOCK; off <<= 1) {
        int t = (threadIdx.x >= off) ? s[threadIdx.x - off] : 0;
        __syncthreads();
        s[threadIdx.x] += t;
        __syncthreads();
    }
    if (i < M) arr[i] = s[threadIdx.x];
    if (threadIdx.x == SCAN_BLOCK - 1) bsum[blockIdx.x] = s[SCAN_BLOCK - 1];
}

__global__ void scan2_kernel(int* __restrict__ bsum, int nb) {
    __shared__ int s[SCAN_BLOCK];
    s[threadIdx.x] = (threadIdx.x < nb) ? bsum[threadIdx.x] : 0;
    __syncthreads();
#pragma unroll
    for (int off = 1; off < SCAN_BLOCK; off <<= 1) {
        int t = (threadIdx.x >= off) ? s[threadIdx.x - off] : 0;
        __syncthreads();
        s[threadIdx.x] += t;
        __syncthreads();
    }
    if (threadIdx.x < nb) bsum[threadIdx.x] = s[threadIdx.x];
}

__global__ void scan3_kernel(int* __restrict__ arr, const int* __restrict__ bsum, int M) {
    int i = blockIdx.x * SCAN_BLOCK + threadIdx.x;
    if (blockIdx.x > 0 && i < M) arr[i] += bsum[blockIdx.x - 1];
}

__global__ void cursor_init_kernel(const int* __restrict__ bscan, const int* __restrict__ bcnt,
                                   int* __restrict__ cursor, int M2) {
    int i = blockIdx.x * blockDim.x + threadIdx.x;
    if (i < M2) cursor[i] = bscan[i] - bcnt[i];
}

// --- xws = (x @ W) * dinv[node] for both types ---
__global__ void xw_kernel(const float* __restrict__ x,
                          const float* __restrict__ Wn, const float* __restrict__ Ws,
                          const float* __restrict__ dinv,
                          float* __restrict__ xws_n, float* __restrict__ xws_s,
                          int n_nodes) {
    __shared__ float wn[64 * 32];
    __shared__ float wsm[64 * 32];
    for (int i = threadIdx.x; i < 64 * 32; i += blockDim.x) {
        wn[i] = Wn[i];
        wsm[i] = Ws[i];
    }
    __syncthreads();
    int lane = threadIdx.x & 31;
    int node = blockIdx.x * (blockDim.x >> 5) + (threadIdx.x >> 5);
    if (node >= n_nodes) return;

    const float4* x4 = (const float4*)(x + (size_t)node * 64);
    float an = 0.f, as = 0.f;
#pragma unroll
    for (int k4 = 0; k4 < 16; ++k4) {
        float4 xv = x4[k4];
        int k = k4 * 4;
        an += xv.x * wn[(k + 0) * 32 + lane] + xv.y * wn[(k + 1) * 32 + lane]
            + xv.z * wn[(k + 2) * 32 + lane] + xv.w * wn[(k + 3) * 32 + lane];
        as += xv.x * wsm[(k + 0) * 32 + lane] + xv.y * wsm[(k + 1) * 32 + lane]
            + xv.z * wsm[(k + 2) * 32 + lane] + xv.w * wsm[(k + 3) * 32 + lane];
    }
    size_t o = (size_t)node * 32 + lane;
    xws_n[o] = an * dinv[node];
    xws_s[o] = as * dinv[n_nodes + node];
}

// --- Pass 1: bucket edges. packed = (dstLocal<<20) | src (src<2^20, dl<128) ---
__global__ void pass1_kernel(const int* __restrict__ ei_n, const int* __restrict__ ei_s,
                             int* __restrict__ cursor, unsigned int* __restrict__ packed,
                             int En, int Es) {
    __shared__ int hist[2 * NBK];
    int tid = threadIdx.x;
    for (int i = tid; i < 2 * NBK; i += blockDim.x) hist[i] = 0;
    __syncthreads();
    int base = blockIdx.x * TILE;
    int Etot = En + Es;
    // Phase A: histogram dsts
#pragma unroll
    for (int i = 0; i < TILE / 256; ++i) {
        int e = base + i * 256 + tid;
        if (e < Etot) {
            int bin;
            if (e < En) bin = ei_n[En + e] >> RBITS;
            else        bin = NBK + (ei_s[Es + (e - En)] >> RBITS);
            atomicAdd(&hist[bin], 1);
        }
    }
    __syncthreads();
    // Phase B: reserve global space per bin; hist becomes running global cursor
    for (int i = tid; i < 2 * NBK; i += blockDim.x) {
        int h = hist[i];
        if (h > 0) hist[i] = atomicAdd(&cursor[i], h);
    }
    __syncthreads();
    // Phase C: write packed entries
#pragma unroll
    for (int i = 0; i < TILE / 256; ++i) {
        int e = base + i * 256 + tid;
        if (e < Etot) {
            int src, dst, bin;
            if (e < En) { src = ei_n[e]; dst = ei_n[En + e]; bin = dst >> RBITS; }
            else { int e2 = e - En; src = ei_s[e2]; dst = ei_s[Es + e2]; bin = NBK + (dst >> RBITS); }
            int pos = atomicAdd(&hist[bin], 1);
            packed[pos] = ((unsigned)(dst & (RS - 1)) << 20) | (unsigned)src;
        }
    }
}

// --- Pass 2: per-bucket LDS scatter-accumulate + epilogue ---
__global__ void __launch_bounds__(512, 2)
pass2_kernel(const unsigned int* __restrict__ packed,
             const int* __restrict__ bcnt, const int* __restrict__ bscan,
             const float* __restrict__ xws_n, const float* __restrict__ xws_s,
             const float* __restrict__ dinv,
             const float* __restrict__ b_n, const float* __restrict__ b_s,
             const float* __restrict__ W_lin, const float* __restrict__ b_lin,
             float* __restrict__ out, int N) {
    __shared__ float accn[RS * 32];
    __shared__ float accs[RS * 32];
    int b = blockIdx.x;
    int tid = threadIdx.x;
    for (int i = tid; i < RS * 32; i += 512) { accn[i] = 0.f; accs[i] = 0.f; }
    __syncthreads();
    int g = tid >> 5;      // 16 groups of 32 lanes
    int f = tid & 31;
    // near edges: bin b
    {
        int e1 = bscan[b];
        int s1 = e1 - bcnt[b];
        int j = s1 + g;
        for (; j + 16 < e1; j += 32) {
            unsigned p0 = packed[j];
            unsigned p1 = packed[j + 16];
            float g0 = xws_n[(size_t)(p0 & 0xFFFFFu) * 32 + f];
            float g1 = xws_n[(size_t)(p1 & 0xFFFFFu) * 32 + f];
            atomicAdd(&accn[(p0 >> 20) * 32 + f], g0);
            atomicAdd(&accn[(p1 >> 20) * 32 + f], g1);
        }
        if (j < e1) {
            unsigned p0 = packed[j];
            float g0 = xws_n[(size_t)(p0 & 0xFFFFFu) * 32 + f];
            atomicAdd(&accn[(p0 >> 20) * 32 + f], g0);
        }
    }
    // similar edges: bin NBK+b
    {
        int e1 = bscan[NBK + b];
        int s1 = e1 - bcnt[NBK + b];
        int j = s1 + g;
        for (; j + 16 < e1; j += 32) {
            unsigned p0 = packed[j];
            unsigned p1 = packed[j + 16];
            float g0 = xws_s[(size_t)(p0 & 0xFFFFFu) * 32 + f];
            float g1 = xws_s[(size_t)(p1 & 0xFFFFFu) * 32 + f];
            atomicAdd(&accs[(p0 >> 20) * 32 + f], g0);
            atomicAdd(&accs[(p1 >> 20) * 32 + f], g1);
        }
        if (j < e1) {
            unsigned p0 = packed[j];
            float g0 = xws_s[(size_t)(p0 & 0xFFFFFu) * 32 + f];
            atomicAdd(&accs[(p0 >> 20) * 32 + f], g0);
        }
    }
    __syncthreads();
    // epilogue: h = relu(acc_n+self)*... ; out[d] = dot(relu(h), W_lin) + b_lin
    int nbase = b * RS;
    for (int idx = tid; idx < RS * 32; idx += 512) {
        int dl = idx >> 5;
        int ff = idx & 31;
        int d = nbase + dl;
        if (d < N) {
            float vn = accn[idx] + xws_n[(size_t)d * 32 + ff];   // + self-loop
            float vs = accs[idx] + xws_s[(size_t)d * 32 + ff];
            float h = vn * dinv[d] + b_n[ff] + vs * dinv[N + d] + b_s[ff];
            h = fmaxf(h, 0.f);
            float p = h * W_lin[ff];
#pragma unroll
            for (int off = 16; off > 0; off >>= 1) p += __shfl_xor(p, off, 32);
            if (ff == 0) out[d] = p + b_lin[0];
        }
    }
}

extern "C" void kernel_launch(void* const* d_in, const int* in_sizes, int n_in,
                              void* d_out, int out_size, void* d_ws, size_t ws_size,
                              hipStream_t stream) {
    const float* x     = (const float*)d_in[0];
    const int*   ei_n  = (const int*)d_in[1];
    const int*   ei_s  = (const int*)d_in[2];
    const float* W_n   = (const float*)d_in[3];
    const float* b_n   = (const float*)d_in[4];
    const float* W_s   = (const float*)d_in[5];
    const float* b_s   = (const float*)d_in[6];
    const float* W_lin = (const float*)d_in[7];
    const float* b_lin = (const float*)d_in[8];
    float* out = (float*)d_out;

    const int N    = in_sizes[0] / 64;   // 100000
    const int En   = in_sizes[1] / 2;    // 3200000
    const int Es   = in_sizes[2] / 2;    // 3200000
    const int Etot = En + Es;
    const int M    = 2 * N;              // node count array length
    const int M2   = 2 * NBK;            // bucket array length (1564)

    // Workspace layout (4-byte words), ~53 MB total:
    // cnt[2N] | dinv[2N] | bcnt[M2] | bscan[M2] | cursor[M2] | bsum[1024]
    // | xws_n[32N] | xws_s[32N] | packed[Etot]
    int*   cnt    = (int*)d_ws;
    float* dinv   = (float*)(cnt + (size_t)M);
    int*   bcnt   = (int*)(dinv + (size_t)M);
    int*   bscan  = bcnt + M2;
    int*   cursor = bscan + M2;
    int*   bsum   = cursor + M2;
    float* xws_n  = (float*)(bsum + 1024);
    float* xws_s  = xws_n + (size_t)32 * N;
    unsigned int* packed = (unsigned int*)(xws_s + (size_t)32 * N);

    hipMemsetAsync(cnt, 0, (size_t)M * sizeof(int), stream);

    count_kernel<<<(Etot + 255) / 256, 256, 0, stream>>>(ei_n, ei_s, cnt, N, En, Es);
    dinv_kernel<<<(M + 255) / 256, 256, 0, stream>>>(cnt, dinv, M);
    bucket_sum_kernel<<<(M2 + 255) / 256, 256, 0, stream>>>(cnt, bcnt, bscan, N, M2);

    int nb = (M2 + SCAN_BLOCK - 1) / SCAN_BLOCK;  // 2
    scan1_kernel<<<nb, SCAN_BLOCK, 0, stream>>>(bscan, bsum, M2);
    scan2_kernel<<<1, SCAN_BLOCK, 0, stream>>>(bsum, nb);
    scan3_kernel<<<nb, SCAN_BLOCK, 0, stream>>>(bscan, bsum, M2);
    cursor_init_kernel<<<(M2 + 255) / 256, 256, 0, stream>>>(bscan, bcnt, cursor, M2);

    xw_kernel<<<(N + 7) / 8, 256, 0, stream>>>(x, W_n, W_s, dinv, xws_n, xws_s, N);

    pass1_kernel<<<(Etot + TILE - 1) / TILE, 256, 0, stream>>>(ei_n, ei_s, cursor, packed, En, Es);

    pass2_kernel<<<NBK, 512, 0, stream>>>(packed, bcnt, bscan, xws_n, xws_s, dinv,
                                          b_n, b_s, W_lin, b_lin, out, N);
}